// Round 6
// baseline (1219.470 us; speedup 1.0000x reference)
//
#include <hip/hip_runtime.h>

#define BSZ 2
#define SEQ 2048
#define DMODEL 512
#define NH 8
#define HDIM 64
#define LROW 2047
#define RJS 2048
#define MAXLEN 1024
#define OUT_ELEMS (BSZ * SEQ * DMODEL)

typedef __bf16 bf16;
typedef bf16 bf16x8 __attribute__((ext_vector_type(8)));
typedef float f32x4 __attribute__((ext_vector_type(4)));

__device__ __forceinline__ f32x4 mfma16(bf16x8 a, bf16x8 b, f32x4 c) {
    return __builtin_amdgcn_mfma_f32_16x16x32_bf16(a, b, c, 0, 0, 0);
}
__device__ __forceinline__ void split2(float x, bf16 &h, bf16 &l) {
    h = (bf16)x;
    l = (bf16)(x - (float)h);
}

// ---------------- K0a: transpose + hi/lo split of Wq/Wk/Wv -> Wt[n][k] ----------------
__global__ __launch_bounds__(256) void prep_w(const float* __restrict__ Wq,
                                              const float* __restrict__ Wk,
                                              const float* __restrict__ Wv,
                                              bf16* __restrict__ wt_hi,
                                              bf16* __restrict__ wt_lo) {
    __shared__ float tile[64][65];
    const int wz = blockIdx.z;
    const float* W = (wz == 0) ? Wq : (wz == 1) ? Wk : Wv;
    bf16* oh = wt_hi + (size_t)wz * DMODEL * DMODEL;
    bf16* ol = wt_lo + (size_t)wz * DMODEL * DMODEL;
    const int k0 = blockIdx.x * 64;
    const int n0 = blockIdx.y * 64;
    const int tid = threadIdx.x;
    for (int e = tid; e < 64 * 64; e += 256) {
        int kk = e >> 6, nn = e & 63;
        tile[nn][kk] = W[(size_t)(k0 + kk) * DMODEL + n0 + nn];
    }
    __syncthreads();
    for (int e = tid; e < 64 * 64; e += 256) {
        int nn = e >> 6, kk = e & 63;
        float x = tile[nn][kk];
        bf16 h, l;
        split2(x, h, l);
        oh[(size_t)(n0 + nn) * DMODEL + k0 + kk] = h;
        ol[(size_t)(n0 + nn) * DMODEL + k0 + kk] = l;
    }
}

// ---------------- K0b: hi/lo split of Er -> [h][2048][64] (row 2047 zeroed) ----------------
__global__ __launch_bounds__(256) void prep_er(const float* __restrict__ Er,
                                               bf16* __restrict__ er_hi,
                                               bf16* __restrict__ er_lo) {
    const int idx = blockIdx.x * 256 + threadIdx.x;
    const int h = idx >> 17;
    const int rem = idx & 131071;
    const int j = rem >> 6, d = rem & 63;
    float x = (j < LROW) ? Er[((size_t)h * LROW + j) * HDIM + d] : 0.f;
    bf16 hh, ll;
    split2(x, hh, ll);
    er_hi[idx] = hh;
    er_lo[idx] = ll;
}

// ---------------- K1: q/k/v projections. q/k -> [b,h,t,hd]; v via swapped operands -> [b,h,hd,t] ----------------
__global__ __launch_bounds__(256) void proj_kernel(
    const float* __restrict__ qin, const float* __restrict__ kin, const float* __restrict__ vin,
    const bf16* __restrict__ wt_hi, const bf16* __restrict__ wt_lo,
    const float* __restrict__ bq, const float* __restrict__ bk, const float* __restrict__ bv,
    bf16* __restrict__ q_hi, bf16* __restrict__ q_lo,
    bf16* __restrict__ k_hi, bf16* __restrict__ k_lo,
    bf16* __restrict__ v_hi, bf16* __restrict__ v_lo) {
    const int wz = blockIdx.z;
    const float* X = (wz == 0) ? qin : (wz == 1) ? kin : vin;
    const float* bias = (wz == 0) ? bq : (wz == 1) ? bk : bv;
    const bf16* wh = wt_hi + (size_t)wz * DMODEL * DMODEL;
    const bf16* wl = wt_lo + (size_t)wz * DMODEL * DMODEL;
    const int tid = threadIdx.x, wv = tid >> 6, lane = tid & 63, g = lane >> 4, c = lane & 15;
    const f32x4 z4 = {0.f, 0.f, 0.f, 0.f};
    f32x4 acc[4] = {z4, z4, z4, z4};

    if (wz < 2) {
        const int m0 = blockIdx.x * 64 + wv * 16;
        const int n0 = blockIdx.y * 64;
        for (int kk = 0; kk < DMODEL; kk += 32) {
            const float* xp = X + (size_t)(m0 + c) * DMODEL + kk + g * 8;
            float4 x0 = *(const float4*)xp;
            float4 x1 = *(const float4*)(xp + 4);
            float fv[8] = {x0.x, x0.y, x0.z, x0.w, x1.x, x1.y, x1.z, x1.w};
            bf16x8 ah, al;
#pragma unroll
            for (int i = 0; i < 8; i++) {
                bf16 hh, ll;
                split2(fv[i], hh, ll);
                ah[i] = hh;
                al[i] = ll;
            }
#pragma unroll
            for (int sub = 0; sub < 4; sub++) {
                const size_t wo = (size_t)(n0 + sub * 16 + c) * DMODEL + kk + g * 8;
                bf16x8 bh = *(const bf16x8*)(wh + wo);
                bf16x8 bl = *(const bf16x8*)(wl + wo);
                acc[sub] = mfma16(ah, bh, acc[sub]);
                acc[sub] = mfma16(ah, bl, acc[sub]);
                acc[sub] = mfma16(al, bh, acc[sub]);
            }
        }
#pragma unroll
        for (int sub = 0; sub < 4; sub++) {
            const int n = n0 + sub * 16 + c;
            const float bval = bias[n];
            const int hh = n >> 6, hd = n & 63;
#pragma unroll
            for (int r = 0; r < 4; r++) {
                const int m = m0 + g * 4 + r;
                const int bb = m >> 11, t = m & (SEQ - 1);
                float val = acc[sub][r] + bval;
                bf16 vh, vl;
                split2(val, vh, vl);
                const size_t o = ((size_t)((bb * NH + hh) * SEQ + t)) * HDIM + hd;
                if (wz == 0) { q_hi[o] = vh; q_lo[o] = vl; }
                else         { k_hi[o] = vh; k_lo[o] = vl; }
            }
        }
    } else {
        const int t0 = blockIdx.x * 64;
        const int hd0 = blockIdx.y * 64 + wv * 16;
        for (int kk = 0; kk < DMODEL; kk += 32) {
            const size_t wo = (size_t)(hd0 + c) * DMODEL + kk + g * 8;
            bf16x8 ah = *(const bf16x8*)(wh + wo);
            bf16x8 al = *(const bf16x8*)(wl + wo);
#pragma unroll
            for (int sub = 0; sub < 4; sub++) {
                const float* xp = X + (size_t)(t0 + sub * 16 + c) * DMODEL + kk + g * 8;
                float4 x0 = *(const float4*)xp;
                float4 x1 = *(const float4*)(xp + 4);
                float fv[8] = {x0.x, x0.y, x0.z, x0.w, x1.x, x1.y, x1.z, x1.w};
                bf16x8 bh, bl;
#pragma unroll
                for (int i = 0; i < 8; i++) {
                    bf16 hh, ll;
                    split2(fv[i], hh, ll);
                    bh[i] = hh;
                    bl[i] = ll;
                }
                acc[sub] = mfma16(ah, bh, acc[sub]);
                acc[sub] = mfma16(al, bh, acc[sub]);
                acc[sub] = mfma16(ah, bl, acc[sub]);
            }
        }
#pragma unroll
        for (int sub = 0; sub < 4; sub++) {
#pragma unroll
            for (int r = 0; r < 4; r++) {
                const int mg = t0 + sub * 16 + c;
                const int bb = mg >> 11, tt = mg & (SEQ - 1);
                const int ng = hd0 + g * 4 + r;
                const int hh = ng >> 6, hdi = ng & 63;
                float val = acc[sub][r] + bias[ng];
                bf16 vh, vl;
                split2(val, vh, vl);
                const size_t o = ((size_t)((bb * NH + hh) * HDIM + hdi)) * SEQ + tt;
                v_hi[o] = vh;
                v_lo[o] = vl;
            }
        }
    }
}

// ---------------- K2: R[b,h,t,j] = q[t] . Er[j]  (GEMM, fp16 output, LDS-staged coalesced store) ----------------
__global__ __launch_bounds__(256) void rel_kernel(
    const bf16* __restrict__ q_hi, const bf16* __restrict__ q_lo,
    const bf16* __restrict__ er_hi, const bf16* __restrict__ er_lo,
    _Float16* __restrict__ R) {
    __shared__ _Float16 rst[4][16][72];
    const int bh = blockIdx.z;
    const int h = bh & 7;
    const int tid = threadIdx.x, wv = tid >> 6, lane = tid & 63, g = lane >> 4, c = lane & 15;
    const int t0 = blockIdx.x * 64 + wv * 16;
    const int j0 = blockIdx.y * 64;
    const bf16* qh = q_hi + (size_t)bh * SEQ * HDIM;
    const bf16* ql = q_lo + (size_t)bh * SEQ * HDIM;
    const bf16* eh = er_hi + (size_t)h * 2048 * HDIM;
    const bf16* el = er_lo + (size_t)h * 2048 * HDIM;
    const f32x4 z4 = {0.f, 0.f, 0.f, 0.f};
    f32x4 acc[4] = {z4, z4, z4, z4};
#pragma unroll
    for (int kc = 0; kc < 2; kc++) {
        const int kk = kc * 32 + g * 8;
        bf16x8 ah = *(const bf16x8*)(qh + (size_t)(t0 + c) * HDIM + kk);
        bf16x8 al = *(const bf16x8*)(ql + (size_t)(t0 + c) * HDIM + kk);
#pragma unroll
        for (int sub = 0; sub < 4; sub++) {
            bf16x8 bh_ = *(const bf16x8*)(eh + (size_t)(j0 + sub * 16 + c) * HDIM + kk);
            bf16x8 bl_ = *(const bf16x8*)(el + (size_t)(j0 + sub * 16 + c) * HDIM + kk);
            acc[sub] = mfma16(ah, bh_, acc[sub]);
            acc[sub] = mfma16(ah, bl_, acc[sub]);
            acc[sub] = mfma16(al, bh_, acc[sub]);
        }
    }
#pragma unroll
    for (int sub = 0; sub < 4; sub++)
#pragma unroll
        for (int r = 0; r < 4; r++)
            rst[wv][g * 4 + r][sub * 16 + c] = (_Float16)acc[sub][r];
#pragma unroll
    for (int it = 0; it < 2; it++) {
        const int e = it * 512 + lane * 8;
        const int row = e >> 6, col = e & 63;
        float4 v = *(const float4*)&rst[wv][row][col];
        *(float4*)&R[((size_t)bh * SEQ + t0 + row) * RJS + j0 + col] = v;
    }
}

// ---------------- K3a: attention compute ----------------
// 8 waves x 256-col strips, chunked by 64 cols: P~ = exp(logit-4) -> per-wave LDS
// staging -> coalesced fp16 store into upper half of attn fp32 row -> PV MFMA.
// l accumulated in f32, block-merged; inv_l written per row; oacc scaled + merged.
__global__ __launch_bounds__(512, 8) void attn_kernel(
    const bf16* __restrict__ q_hi, const bf16* __restrict__ q_lo,
    const bf16* __restrict__ k_hi, const bf16* __restrict__ k_lo,
    const bf16* __restrict__ v_hi, const bf16* __restrict__ v_lo,
    const _Float16* __restrict__ R, const int* __restrict__ layer_p,
    float* out, float* attn, float* __restrict__ inv_l_buf) {
    __shared__ __align__(16) char smem_raw[35392];
    _Float16 (*staged)[16][72] = (_Float16 (*)[16][72])smem_raw;  // [8][16][72] = 18432 B
    float (*obuf)[16][68] = (float (*)[16][68])smem_raw;          // 34816 B (aliases staged; used after)
    float* ml  = (float*)(smem_raw + 34816);                      // [8][16]
    float* fml = (float*)(smem_raw + 35328);                      // [16] inv_l

    const int bh = blockIdx.y;
    const int b = bh >> 3, h = bh & 7;
    const int tid = threadIdx.x, wv = tid >> 6, lane = tid & 63, g = lane >> 4, c = lane & 15;
    const int t0 = blockIdx.x * 16;
    const int layer = layer_p[0];
    const int strd = 1 << layer;
    const int dil = min(1 + (SEQ - 1) / strd, MAXLEN);
    const int sq0 = wv * 256;   // this wave's s-strip [sq0, sq0+256)

    const bf16* qh_p = q_hi + ((size_t)bh * SEQ + t0) * HDIM;
    const bf16* ql_p = q_lo + ((size_t)bh * SEQ + t0) * HDIM;
    const bf16* kh_p = k_hi + (size_t)bh * SEQ * HDIM;
    const bf16* kl_p = k_lo + (size_t)bh * SEQ * HDIM;
    const bf16* vh_p = v_hi + (size_t)bh * HDIM * SEQ;
    const bf16* vl_p = v_lo + (size_t)bh * HDIM * SEQ;
    const _Float16* Rp = R + (size_t)bh * SEQ * RJS;
    char* attn_bytes = (char*)(attn + (size_t)bh * SEQ * SEQ);   // row stride 8192 B

    bf16x8 qh[2], ql[2];
#pragma unroll
    for (int kc = 0; kc < 2; kc++) {
        qh[kc] = *(const bf16x8*)(qh_p + c * HDIM + kc * 32 + g * 8);
        ql[kc] = *(const bf16x8*)(ql_p + c * HDIM + kc * 32 + g * 8);
    }

    float l_r[4] = {0.f, 0.f, 0.f, 0.f};
    const f32x4 z4 = {0.f, 0.f, 0.f, 0.f};
    f32x4 oacc[4] = {z4, z4, z4, z4};
    const int frow = lane >> 2;          // flush row
    const int fq = lane & 3;             // flush quad (32 B each)

#pragma unroll
    for (int ch = 0; ch < 4; ch++) {
        const int sc0 = sq0 + ch * 64;
        // ---- 4 logit tiles -> exp -> staged fp16 ----
#pragma unroll
        for (int ti = 0; ti < 4; ti++) {
            const int s0 = sc0 + ti * 16;
            f32x4 aA = z4, aB = z4, aC = z4;
#pragma unroll
            for (int kc = 0; kc < 2; kc++) {
                const size_t ko = (size_t)(s0 + c) * HDIM + kc * 32 + g * 8;
                bf16x8 kh8 = *(const bf16x8*)(kh_p + ko);
                bf16x8 kl8 = *(const bf16x8*)(kl_p + ko);
                aA = mfma16(qh[kc], kh8, aA);
                aB = mfma16(qh[kc], kl8, aB);
                aC = mfma16(ql[kc], kh8, aC);
            }
            f32x4 lg = aA + aB + aC;
#pragma unroll
            for (int r = 0; r < 4; r++) {
                const int t = t0 + g * 4 + r;
                const int dd = s0 + c - t;
                const int mm = dd >> layer;
                const bool ok = ((dd & (strd - 1)) == 0) & (mm > -dil) & (mm < dil);
                const int j = ok ? 1023 + mm : 2047;    // R row j=2047 is exactly 0
                const float rel = (float)Rp[(size_t)t * RJS + j];
                const float x = (lg[r] + rel) * 0.125f - 4.0f;
                const float e = __expf(x);
                l_r[r] += e;
                staged[wv][g * 4 + r][ti * 16 + c] = (_Float16)e;
            }
        }
        // ---- flush chunk to global fp16 (upper half of fp32 row), 128 B/row ----
        {
            const _Float16* sp = &staged[wv][frow][fq * 16];
            float4 s0v = *(const float4*)sp;
            float4 s1v = *(const float4*)(sp + 8);
            char* dst = attn_bytes + (size_t)(t0 + frow) * 8192 + 4096 + (size_t)(sc0 + fq * 16) * 2;
            *(float4*)dst = s0v;
            *(float4*)(dst + 16) = s1v;
        }
        // ---- PV on the chunk (unnormalized P~) ----
#pragma unroll
        for (int kc = 0; kc < 2; kc++) {
            _Float16 pf16[8];
            *(float4*)pf16 = *(const float4*)&staged[wv][c][kc * 32 + g * 8];
            bf16x8 pah, pal;
#pragma unroll
            for (int i = 0; i < 8; i++) {
                bf16 hh, ll;
                split2((float)pf16[i], hh, ll);
                pah[i] = hh;
                pal[i] = ll;
            }
#pragma unroll
            for (int sub = 0; sub < 4; sub++) {
                const size_t vo = (size_t)(sub * 16 + c) * SEQ + sc0 + kc * 32 + g * 8;
                bf16x8 vh8 = *(const bf16x8*)(vh_p + vo);
                bf16x8 vl8 = *(const bf16x8*)(vl_p + vo);
                oacc[sub] = mfma16(pah, vh8, oacc[sub]);
                oacc[sub] = mfma16(pah, vl8, oacc[sub]);
                oacc[sub] = mfma16(pal, vh8, oacc[sub]);
            }
        }
    }

    // ---- merge l across 16 c-lanes, then across waves ----
#pragma unroll
    for (int mask = 1; mask < 16; mask <<= 1)
#pragma unroll
        for (int r = 0; r < 4; r++) l_r[r] += __shfl_xor(l_r[r], mask);
    if (c == 0) {
#pragma unroll
        for (int r = 0; r < 4; r++) ml[wv * 16 + g * 4 + r] = l_r[r];
    }
    __syncthreads();
    if (tid < 16) {
        float l = 0.f;
#pragma unroll
        for (int w = 0; w < 8; w++) l += ml[w * 16 + tid];
        const float inv = 1.f / l;
        fml[tid] = inv;
        inv_l_buf[(size_t)bh * SEQ + t0 + tid] = inv;
    }
    __syncthreads();
    float inv_l[4];
#pragma unroll
    for (int r = 0; r < 4; r++) inv_l[r] = fml[g * 4 + r];
#pragma unroll
    for (int sub = 0; sub < 4; sub++)
#pragma unroll
        for (int r = 0; r < 4; r++) oacc[sub][r] *= inv_l[r];

    // ---- merge PV partials across the 8 waves ----
    __syncthreads();   // staged dead; obuf aliases it
#pragma unroll
    for (int sub = 0; sub < 4; sub++)
#pragma unroll
        for (int r = 0; r < 4; r++)
            obuf[wv][g * 4 + r][sub * 16 + c] = oacc[sub][r];
    __syncthreads();
    if (tid < 256) {
        const int e = tid * 4;
        const int row = e >> 6, col = e & 63;
        float4 s = *(const float4*)&obuf[0][row][col];
#pragma unroll
        for (int w = 1; w < 8; w++) {
            float4 sw = *(const float4*)&obuf[w][row][col];
            s.x += sw.x; s.y += sw.y; s.z += sw.z; s.w += sw.w;
        }
        *(float4*)&out[((size_t)b * SEQ + t0 + row) * DMODEL + h * HDIM + col] = s;
    }
}

// ---------------- K3b: finalize probs: fp16 P~ (upper half of row) -> normalized fp32 row ----------------
__global__ __launch_bounds__(256) void finalize_kernel(float* attn, const float* __restrict__ inv_l_buf) {
    const int row = blockIdx.x;            // over BSZ*NH*SEQ rows
    const int tid = threadIdx.x;
    char* base = (char*)attn + (size_t)row * 8192;
    const float inv = inv_l_buf[row];
    _Float16 v16[8];
    *(float4*)v16 = *((const float4*)(base + 4096) + tid);
    __syncthreads();                        // all reads done before any write hits upper half
    float4 o0, o1;
    o0.x = (float)v16[0] * inv; o0.y = (float)v16[1] * inv;
    o0.z = (float)v16[2] * inv; o0.w = (float)v16[3] * inv;
    o1.x = (float)v16[4] * inv; o1.y = (float)v16[5] * inv;
    o1.z = (float)v16[6] * inv; o1.w = (float)v16[7] * inv;
    float4* dst = (float4*)base + tid * 2;
    dst[0] = o0;
    dst[1] = o1;
}

extern "C" void kernel_launch(void* const* d_in, const int* in_sizes, int n_in,
                              void* d_out, int out_size, void* d_ws, size_t ws_size,
                              hipStream_t stream) {
    const float* query = (const float*)d_in[0];
    const float* key = (const float*)d_in[1];
    const float* value = (const float*)d_in[2];
    const float* Wq = (const float*)d_in[3];
    const float* bq = (const float*)d_in[4];
    const float* Wk = (const float*)d_in[5];
    const float* bk = (const float*)d_in[6];
    const float* Wv = (const float*)d_in[7];
    const float* bv = (const float*)d_in[8];
    const float* Er = (const float*)d_in[9];
    const int* layer = (const int*)d_in[10];

    char* ws = (char*)d_ws;
    size_t off = 0;
    bf16* wt_hi = (bf16*)(ws + off); off += (size_t)3 * DMODEL * DMODEL * 2;
    bf16* wt_lo = (bf16*)(ws + off); off += (size_t)3 * DMODEL * DMODEL * 2;
    bf16* er_hi = (bf16*)(ws + off); off += (size_t)NH * 2048 * HDIM * 2;
    bf16* er_lo = (bf16*)(ws + off); off += (size_t)NH * 2048 * HDIM * 2;
    bf16* q_hi = (bf16*)(ws + off); off += (size_t)BSZ * NH * SEQ * HDIM * 2;
    bf16* q_lo = (bf16*)(ws + off); off += (size_t)BSZ * NH * SEQ * HDIM * 2;
    bf16* k_hi = (bf16*)(ws + off); off += (size_t)BSZ * NH * SEQ * HDIM * 2;
    bf16* k_lo = (bf16*)(ws + off); off += (size_t)BSZ * NH * SEQ * HDIM * 2;
    bf16* v_hi = (bf16*)(ws + off); off += (size_t)BSZ * NH * SEQ * HDIM * 2;
    bf16* v_lo = (bf16*)(ws + off); off += (size_t)BSZ * NH * SEQ * HDIM * 2;
    _Float16* Rbuf = (_Float16*)(ws + off); off += (size_t)BSZ * NH * SEQ * RJS * 2;
    float* inv_l_buf = (float*)(ws + off); off += (size_t)BSZ * NH * SEQ * 4;

    float* out = (float*)d_out;
    float* attn = out + OUT_ELEMS;

    prep_w<<<dim3(8, 8, 3), 256, 0, stream>>>(Wq, Wk, Wv, wt_hi, wt_lo);
    prep_er<<<(NH * 2048 * HDIM) / 256, 256, 0, stream>>>(Er, er_hi, er_lo);
    proj_kernel<<<dim3(64, 8, 3), 256, 0, stream>>>(query, key, value, wt_hi, wt_lo,
                                                    bq, bk, bv,
                                                    q_hi, q_lo, k_hi, k_lo, v_hi, v_lo);
    rel_kernel<<<dim3(32, 32, 16), 256, 0, stream>>>(q_hi, q_lo, er_hi, er_lo, Rbuf);
    attn_kernel<<<dim3(128, 16), 512, 0, stream>>>(q_hi, q_lo, k_hi, k_lo, v_hi, v_lo,
                                                   Rbuf, layer, out, attn, inv_l_buf);
    finalize_kernel<<<BSZ * NH * SEQ, 256, 0, stream>>>(attn, inv_l_buf);
}